// Round 4
// baseline (457.999 us; speedup 1.0000x reference)
//
#include <hip/hip_runtime.h>

// TTRFluxLayer R4: phi occupancy fix (R3 phi was 1 block/CU, barrier-serialized).
// phi: M=64 blocks, 512thr, wave tile 64x32. w1 in regs (8 frags), w2 streamed
//      from global via 3-deep reg ring (L2-resident). LDS 51KB -> 2 blocks/CU,
//      VGPR forced <=128 via __launch_bounds__(512,4).
// s:   f-split blocks (LDS 70KB -> 2 blocks/CU).
// pfx: vectorized f16x8 per thread.
// ws: w1h 64K | w2h 128K | qp 48M | kp 48M | kpT/Wf 48M | S/Wr 48M | vT 24M

typedef __attribute__((ext_vector_type(8))) _Float16 f16x8;
typedef __attribute__((ext_vector_type(4))) _Float16 f16x4;
typedef __attribute__((ext_vector_type(4))) float f32x4;

#define MFMA16(a, b, c) __builtin_amdgcn_mfma_f32_16x16x32_f16((a), (b), (c), 0, 0, 0)

constexpr int BH   = 24;
constexpr int NSEQ = 4096;
constexpr int DD   = 128;
constexpr int FF   = 256;
constexpr int CHK  = 128;
constexpr int NC   = NSEQ / CHK;     // 32
constexpr int NROWS = BH * NSEQ;     // 98304

// ---------------- k0: weight convert ----------------
__global__ void prep_kernel(const float* __restrict__ w1, const float* __restrict__ w2,
                            _Float16* __restrict__ w1h, _Float16* __restrict__ w2h) {
  int i = blockIdx.x * 256 + threadIdx.x;
  if (i < FF * DD) w1h[i] = (_Float16)w1[i];
  if (i < FF * FF) w2h[i] = (_Float16)w2[i];
}

// ---------------- k0b: v -> vT fp16 [bh][d][s] ----------------
__global__ void vt_kernel(const float* __restrict__ v, _Float16* __restrict__ vT) {
  __shared__ __align__(16) _Float16 lt[128][136];
  int blk = blockIdx.x;
  int c = blk & 31, bh = blk >> 5;
  const float* vc = v + ((size_t)bh * NSEQ + c * CHK) * DD;
  int tid = threadIdx.x;
#pragma unroll
  for (int it = 0; it < 16; ++it) {
    int flat = it * 1024 + tid * 4;
    int s = flat >> 7, d0 = flat & 127;
    float4 xv = *(const float4*)&vc[(size_t)s * DD + d0];
    lt[d0 + 0][s] = (_Float16)xv.x;
    lt[d0 + 1][s] = (_Float16)xv.y;
    lt[d0 + 2][s] = (_Float16)xv.z;
    lt[d0 + 3][s] = (_Float16)xv.w;
  }
  __syncthreads();
#pragma unroll
  for (int it = 0; it < 8; ++it) {
    int flat = it * 256 + tid;
    int d = flat >> 4, sg = flat & 15;
    *(f16x8*)&vT[((size_t)bh * DD + d) * NSEQ + c * CHK + sg * 8] =
        *(const f16x8*)&lt[d][sg * 8];
  }
}

// ---------------- k1: phi (fused 2-GEMM + SiLU) ----------------
// M=64 rows/block, 512 thr (8 waves), wave tile 64m x 32f.
__global__ __launch_bounds__(512, 4)
void phi_kernel(const float* __restrict__ q, const float* __restrict__ k,
                const float* __restrict__ b1, const float* __restrict__ b2,
                const _Float16* __restrict__ w1h, const _Float16* __restrict__ w2h,
                _Float16* __restrict__ qp, _Float16* __restrict__ kp,
                _Float16* __restrict__ kpT) {
  __shared__ __align__(16) _Float16 xs[64][136];  // 17.4 KB
  __shared__ __align__(16) _Float16 hs[64][264];  // 33.8 KB
  int blk = blockIdx.x;
  const float* src;
  _Float16* dst;
  bool isk;
  int rb;
  if (blk < NROWS / 64) { src = q; dst = qp; rb = blk * 64; isk = false; }
  else                  { src = k; dst = kp; rb = (blk - NROWS / 64) * 64; isk = true; }
  int tid = threadIdx.x;
  int lane = tid & 63, wv = tid >> 6, lr = lane & 15, lq = lane >> 4;
  int wn = wv;  // f-strip of 32 per wave

  // --- w1 frags into regs (8 frags = 32 VGPR); latency hides behind x staging ---
  f16x8 w1r[4][2];
#pragma unroll
  for (int ks = 0; ks < 4; ++ks)
#pragma unroll
    for (int fn = 0; fn < 2; ++fn)
      w1r[ks][fn] = *(const f16x8*)&w1h[(wn * 32 + fn * 16 + lr) * DD + ks * 32 + lq * 8];

  // --- stage x (64x128 f32 -> f16) ---
#pragma unroll
  for (int it = 0; it < 4; ++it) {
    int flat = it * 2048 + tid * 4;
    int r = flat >> 7, c = flat & 127;
    float4 xv = *(const float4*)&src[(size_t)(rb + r) * DD + c];
    f16x4 hv = {(_Float16)xv.x, (_Float16)xv.y, (_Float16)xv.z, (_Float16)xv.w};
    *(f16x4*)&xs[r][c] = hv;
  }
  __syncthreads();

  // --- GEMM1: 64x32 out, K=128, weights in regs ---
  f32x4 acc[4][2] = {};
#pragma unroll
  for (int ks = 0; ks < 4; ++ks) {
    f16x8 av[4];
#pragma unroll
    for (int im = 0; im < 4; ++im)
      av[im] = *(const f16x8*)&xs[im * 16 + lr][ks * 32 + lq * 8];
#pragma unroll
    for (int fn = 0; fn < 2; ++fn)
#pragma unroll
      for (int im = 0; im < 4; ++im) acc[im][fn] = MFMA16(av[im], w1r[ks][fn], acc[im][fn]);
  }

  // --- SiLU -> hs (no barrier needed before: hs disjoint from xs) ---
#pragma unroll
  for (int im = 0; im < 4; ++im)
#pragma unroll
    for (int fn = 0; fn < 2; ++fn) {
      int f = wn * 32 + fn * 16 + lr;
      float bb = b1[f];
      int r0 = im * 16 + lq * 4;
#pragma unroll
      for (int r = 0; r < 4; ++r) {
        float xv = acc[im][fn][r] + bb;
        hs[r0 + r][f] = (_Float16)(xv / (1.0f + __expf(-xv)));
      }
    }

  // --- prefetch w2 ring for ks=0,1 (before the barrier: overlaps it) ---
  f16x8 bw[3][2];
#pragma unroll
  for (int fn = 0; fn < 2; ++fn) {
    int g = wn * 32 + fn * 16 + lr;
    bw[0][fn] = *(const f16x8*)&w2h[(size_t)g * FF + 0 * 32 + lq * 8];
    bw[1][fn] = *(const f16x8*)&w2h[(size_t)g * FF + 1 * 32 + lq * 8];
  }
  __syncthreads();

  // --- GEMM2: 64x32 out, K=256, w2 streamed via 3-deep reg ring ---
  f32x4 ac2[4][2] = {};
#pragma unroll
  for (int ks = 0; ks < 8; ++ks) {
    if (ks < 6) {
#pragma unroll
      for (int fn = 0; fn < 2; ++fn) {
        int g = wn * 32 + fn * 16 + lr;
        bw[(ks + 2) % 3][fn] = *(const f16x8*)&w2h[(size_t)g * FF + (ks + 2) * 32 + lq * 8];
      }
    }
    f16x8 av[4];
#pragma unroll
    for (int im = 0; im < 4; ++im)
      av[im] = *(const f16x8*)&hs[im * 16 + lr][ks * 32 + lq * 8];
#pragma unroll
    for (int fn = 0; fn < 2; ++fn)
#pragma unroll
      for (int im = 0; im < 4; ++im) ac2[im][fn] = MFMA16(av[im], bw[ks % 3][fn], ac2[im][fn]);
  }

  // --- epilogue: qp/kp row-major; k also -> kpT[bh][f][s] ---
  int bh = rb >> 12, s0 = rb & 4095;
#pragma unroll
  for (int im = 0; im < 4; ++im)
#pragma unroll
    for (int fn = 0; fn < 2; ++fn) {
      int g = wn * 32 + fn * 16 + lr;
      float bb = b2[g];
      int r0 = im * 16 + lq * 4;
#pragma unroll
      for (int r = 0; r < 4; ++r) {
        _Float16 val = (_Float16)(ac2[im][fn][r] + bb);
        dst[(size_t)(rb + r0 + r) * FF + g] = val;
        if (isk) kpT[((size_t)bh * FF + g) * NSEQ + s0 + r0 + r] = val;
      }
    }
}

// ---------------- k2: S^T[d][f] per chunk (f-split blocks) ----------------
__global__ __launch_bounds__(512, 4)
void s_kernel(const _Float16* __restrict__ vT, const _Float16* __restrict__ kpT,
              _Float16* __restrict__ S) {
  __shared__ __align__(16) _Float16 vt[128][136];  // 34.8 KB
  __shared__ __align__(16) _Float16 kt[128][136];  // 34.8 KB
  int blk = blockIdx.x;
  int fh = blk & 1, c = (blk >> 1) & 31, bh = blk >> 6;
  int tid = threadIdx.x;
#pragma unroll
  for (int it = 0; it < 4; ++it) {
    int flat = it * 512 + tid;
    int d = flat >> 4, sg = flat & 15;
    *(f16x8*)&vt[d][sg * 8] = *(const f16x8*)&vT[((size_t)bh * DD + d) * NSEQ + c * CHK + sg * 8];
  }
#pragma unroll
  for (int it = 0; it < 4; ++it) {
    int flat = it * 512 + tid;
    int f = flat >> 4, sg = flat & 15;
    *(f16x8*)&kt[f][sg * 8] =
        *(const f16x8*)&kpT[((size_t)bh * FF + fh * 128 + f) * NSEQ + c * CHK + sg * 8];
  }
  __syncthreads();
  int lane = tid & 63, wv = tid >> 6, lr = lane & 15, lq = lane >> 4;
  int wmd = wv & 1, wnf = wv >> 1;  // 2 x 64d, 4 x 32f
  f32x4 acc[4][2] = {};
#pragma unroll
  for (int ks = 0; ks < 4; ++ks) {
    f16x8 av[4];
#pragma unroll
    for (int im = 0; im < 4; ++im)
      av[im] = *(const f16x8*)&vt[wmd * 64 + im * 16 + lr][ks * 32 + lq * 8];
#pragma unroll
    for (int fn = 0; fn < 2; ++fn) {
      f16x8 bv = *(const f16x8*)&kt[wnf * 32 + fn * 16 + lr][ks * 32 + lq * 8];
#pragma unroll
      for (int im = 0; im < 4; ++im) acc[im][fn] = MFMA16(av[im], bv, acc[im][fn]);
    }
  }
  _Float16* Sp = S + ((size_t)bh * NC + c) * (size_t)(DD * FF);
#pragma unroll
  for (int im = 0; im < 4; ++im)
#pragma unroll
    for (int fn = 0; fn < 2; ++fn) {
      int f = fh * 128 + wnf * 32 + fn * 16 + lr;
#pragma unroll
      for (int r = 0; r < 4; ++r) {
        int d = wmd * 64 + im * 16 + lq * 4 + r;
        Sp[(size_t)d * FF + f] = (_Float16)acc[im][fn][r];
      }
    }
}

// ---------------- k3: prefix->Wf, suffix in-place (->Wr), vectorized x8 ----
__global__ void prefix_kernel(_Float16* S_Wr, _Float16* __restrict__ Wf) {
  size_t t8 = (size_t)blockIdx.x * 256 + threadIdx.x;  // over BH*4096 groups of 8
  int bh = (int)(t8 >> 12);
  int df8 = (int)(t8 & 4095);
  size_t base = (size_t)bh * NC * 32768 + (size_t)df8 * 8;
  f16x8 vals[NC];
#pragma unroll
  for (int c = 0; c < NC; ++c) vals[c] = *(const f16x8*)&S_Wr[base + (size_t)c * 32768];
  float run[8] = {};
#pragma unroll
  for (int c = 0; c < NC; ++c) {
    f16x8 w;
#pragma unroll
    for (int j = 0; j < 8; ++j) { w[j] = (_Float16)run[j]; run[j] += (float)vals[c][j]; }
    *(f16x8*)&Wf[base + (size_t)c * 32768] = w;
  }
#pragma unroll
  for (int j = 0; j < 8; ++j) run[j] = 0.f;
#pragma unroll
  for (int c = NC - 1; c >= 0; --c) {
    f16x8 w;
#pragma unroll
    for (int j = 0; j < 8; ++j) { w[j] = (_Float16)run[j]; run[j] += (float)vals[c][j]; }
    *(f16x8*)&S_Wr[base + (size_t)c * 32768] = w;
  }
}

// ---------------- k4: fused phase-2 scan (full chunk per block) ----------------
__global__ __launch_bounds__(512, 2)
void scan_kernel(const _Float16* __restrict__ qp, const _Float16* __restrict__ kp,
                 const _Float16* __restrict__ vT, const _Float16* __restrict__ Wf,
                 const _Float16* __restrict__ Wr, float* __restrict__ out) {
  __shared__ __align__(16) _Float16 vt[128][136];
  __shared__ __align__(16) _Float16 P[128][136];
  int blk = blockIdx.x;
  int c = blk & 31, bh = blk >> 5;
  const _Float16* qpc = qp + ((size_t)bh * NSEQ + c * CHK) * FF;
  const _Float16* kpc = kp + ((size_t)bh * NSEQ + c * CHK) * FF;
  int tid = threadIdx.x, lane = tid & 63, wv = tid >> 6, lr = lane & 15, lq = lane >> 4;
  int wm = wv & 3, wn = wv >> 2;

  f16x8 aq[2][8];
#pragma unroll
  for (int im = 0; im < 2; ++im)
#pragma unroll
    for (int ks = 0; ks < 8; ++ks)
      aq[im][ks] = *(const f16x8*)&qpc[(size_t)(wm * 32 + im * 16 + lr) * FF + ks * 32 + lq * 8];
#pragma unroll
  for (int it = 0; it < 4; ++it) {
    int flat = it * 512 + tid;
    int d = flat >> 4, sg = flat & 15;
    *(f16x8*)&vt[d][sg * 8] = *(const f16x8*)&vT[((size_t)bh * DD + d) * NSEQ + c * CHK + sg * 8];
  }
  f16x8 bk[2][8];
#pragma unroll
  for (int ks = 0; ks < 8; ++ks)
    bk[0][ks] = *(const f16x8*)&kpc[(size_t)(wn * 64 + lr) * FF + ks * 32 + lq * 8];
  f32x4 pacc[2][4] = {};
#pragma unroll
  for (int j = 0; j < 4; ++j) {
    int cur = j & 1;
    if (j < 3)
#pragma unroll
      for (int ks = 0; ks < 8; ++ks)
        bk[cur ^ 1][ks] = *(const f16x8*)&kpc[(size_t)(wn * 64 + (j + 1) * 16 + lr) * FF + ks * 32 + lq * 8];
#pragma unroll
    for (int ks = 0; ks < 8; ++ks)
#pragma unroll
      for (int im = 0; im < 2; ++im)
        pacc[im][j] = MFMA16(aq[im][ks], bk[cur][ks], pacc[im][j]);
  }
#pragma unroll
  for (int im = 0; im < 2; ++im)
#pragma unroll
    for (int j = 0; j < 4; ++j)
#pragma unroll
      for (int r = 0; r < 4; ++r)
        P[wm * 32 + im * 16 + lq * 4 + r][wn * 64 + j * 16 + lr] = (_Float16)pacc[im][j][r];

  const _Float16* Wfc = Wf + ((size_t)bh * NC + c) * (size_t)(DD * FF);
  const _Float16* Wrc = Wr + ((size_t)bh * NC + c) * (size_t)(DD * FF);
  f16x8 bf[8], br[8];
#pragma unroll
  for (int ks = 0; ks < 8; ++ks) {
    int d = wn * 64 + lr;
    bf[ks] = *(const f16x8*)&Wfc[(size_t)d * FF + ks * 32 + lq * 8];
    br[ks] = *(const f16x8*)&Wrc[(size_t)d * FF + ks * 32 + lq * 8];
  }
  __syncthreads();

  f32x4 af[2][4] = {}, ar[2][4] = {};
#pragma unroll
  for (int jd = 0; jd < 4; ++jd) {
#pragma unroll
    for (int ks = 0; ks < 8; ++ks)
#pragma unroll
      for (int im = 0; im < 2; ++im) {
        af[im][jd] = MFMA16(aq[im][ks], bf[ks], af[im][jd]);
        ar[im][jd] = MFMA16(aq[im][ks], br[ks], ar[im][jd]);
      }
    if (jd < 3)
#pragma unroll
      for (int ks = 0; ks < 8; ++ks) {
        int d = wn * 64 + (jd + 1) * 16 + lr;
        bf[ks] = *(const f16x8*)&Wfc[(size_t)d * FF + ks * 32 + lq * 8];
        br[ks] = *(const f16x8*)&Wrc[(size_t)d * FF + ks * 32 + lq * 8];
      }
    {
      int ks = jd;
      f16x8 bv[4];
#pragma unroll
      for (int jd2 = 0; jd2 < 4; ++jd2)
        bv[jd2] = *(const f16x8*)&vt[wn * 64 + jd2 * 16 + lr][ks * 32 + lq * 8];
#pragma unroll
      for (int im = 0; im < 2; ++im) {
        int irow = wm * 32 + im * 16 + lr;
        f16x8 p = *(const f16x8*)&P[irow][ks * 32 + lq * 8];
        f16x8 pf = p, pr = p;
#pragma unroll
        for (int jj = 0; jj < 8; ++jj) {
          int s = ks * 32 + lq * 8 + jj;
          pf[jj] = (s <= irow) ? p[jj] : (_Float16)0.0f;
          pr[jj] = (s >= irow) ? p[jj] : (_Float16)0.0f;
        }
#pragma unroll
        for (int jd2 = 0; jd2 < 4; ++jd2) {
          af[im][jd2] = MFMA16(pf, bv[jd2], af[im][jd2]);
          ar[im][jd2] = MFMA16(pr, bv[jd2], ar[im][jd2]);
        }
      }
    }
  }

  float* oc = out + ((size_t)bh * NSEQ + c * CHK) * DD;
#pragma unroll
  for (int im = 0; im < 2; ++im)
#pragma unroll
    for (int jd = 0; jd < 4; ++jd) {
      int d = wn * 64 + jd * 16 + lr;
#pragma unroll
      for (int r = 0; r < 4; ++r) {
        int il = wm * 32 + im * 16 + lq * 4 + r;
        int gi = c * CHK + il;
        oc[(size_t)il * DD + d] = af[im][jd][r] / (float)(gi + 1) + ar[im][jd][r] / (float)(NSEQ - gi);
      }
    }
}

// ---------------- launcher ----------------
extern "C" void kernel_launch(void* const* d_in, const int* in_sizes, int n_in,
                              void* d_out, int out_size, void* d_ws, size_t ws_size,
                              hipStream_t stream) {
  const float* q  = (const float*)d_in[0];
  const float* k  = (const float*)d_in[1];
  const float* v  = (const float*)d_in[2];
  const float* w1 = (const float*)d_in[3];
  const float* b1 = (const float*)d_in[4];
  const float* w2 = (const float*)d_in[5];
  const float* b2 = (const float*)d_in[6];
  float* out = (float*)d_out;

  char* ws = (char*)d_ws;
  const size_t SZ = 50331648ull;
  _Float16* w1h = (_Float16*)(ws);
  _Float16* w2h = (_Float16*)(ws + 65536);
  _Float16* qp  = (_Float16*)(ws + 196608);
  _Float16* kp  = (_Float16*)(ws + 196608 + SZ);
  _Float16* kpT = (_Float16*)(ws + 196608 + 2 * SZ);
  _Float16* S   = (_Float16*)(ws + 196608 + 3 * SZ);
  _Float16* vT  = (_Float16*)(ws + 196608 + 4 * SZ);
  _Float16* Wf  = kpT;
  _Float16* Wr  = S;

  prep_kernel<<<dim3(256), dim3(256), 0, stream>>>(w1, w2, w1h, w2h);
  vt_kernel<<<dim3(BH * NC), dim3(256), 0, stream>>>(v, vT);
  phi_kernel<<<dim3(2 * NROWS / 64), dim3(512), 0, stream>>>(q, k, b1, b2, w1h, w2h, qp, kp, kpT);
  s_kernel<<<dim3(BH * NC * 2), dim3(512), 0, stream>>>(vT, kpT, S);
  prefix_kernel<<<dim3(BH * 4096 / 256), dim3(256), 0, stream>>>(S, Wf);
  scan_kernel<<<dim3(BH * NC), dim3(512), 0, stream>>>(qp, kp, vT, Wf, Wr, out);
}

// Round 5
// 453.127 us; speedup vs baseline: 1.0108x; 1.0108x over previous
//
#include <hip/hip_runtime.h>

// TTRFluxLayer R5: kill the kpT scatter-store (64-line/instr TA serialization).
// phi: no kpT output; hs padded to 272 (conflict-free SiLU scalar LDS writes).
// s:   stages row-major kp tiles (coalesced), builds B-frags via 8x ds_read_u16
//      + pack (lane-consecutive -> conflict-free). kpT global buffer deleted.
// ws: w1h 64K | w2h 128K | qp 48M | kp 48M | Wf 48M | S/Wr 48M | vT 24M

typedef __attribute__((ext_vector_type(8))) _Float16 f16x8;
typedef __attribute__((ext_vector_type(4))) _Float16 f16x4;
typedef __attribute__((ext_vector_type(4))) float f32x4;

#define MFMA16(a, b, c) __builtin_amdgcn_mfma_f32_16x16x32_f16((a), (b), (c), 0, 0, 0)

constexpr int BH   = 24;
constexpr int NSEQ = 4096;
constexpr int DD   = 128;
constexpr int FF   = 256;
constexpr int CHK  = 128;
constexpr int NC   = NSEQ / CHK;     // 32
constexpr int NROWS = BH * NSEQ;     // 98304

// ---------------- k0: weight convert ----------------
__global__ void prep_kernel(const float* __restrict__ w1, const float* __restrict__ w2,
                            _Float16* __restrict__ w1h, _Float16* __restrict__ w2h) {
  int i = blockIdx.x * 256 + threadIdx.x;
  if (i < FF * DD) w1h[i] = (_Float16)w1[i];
  if (i < FF * FF) w2h[i] = (_Float16)w2[i];
}

// ---------------- k0b: v -> vT fp16 [bh][d][s] ----------------
__global__ void vt_kernel(const float* __restrict__ v, _Float16* __restrict__ vT) {
  __shared__ __align__(16) _Float16 lt[128][136];
  int blk = blockIdx.x;
  int c = blk & 31, bh = blk >> 5;
  const float* vc = v + ((size_t)bh * NSEQ + c * CHK) * DD;
  int tid = threadIdx.x;
#pragma unroll
  for (int it = 0; it < 16; ++it) {
    int flat = it * 1024 + tid * 4;
    int s = flat >> 7, d0 = flat & 127;
    float4 xv = *(const float4*)&vc[(size_t)s * DD + d0];
    lt[d0 + 0][s] = (_Float16)xv.x;
    lt[d0 + 1][s] = (_Float16)xv.y;
    lt[d0 + 2][s] = (_Float16)xv.z;
    lt[d0 + 3][s] = (_Float16)xv.w;
  }
  __syncthreads();
#pragma unroll
  for (int it = 0; it < 8; ++it) {
    int flat = it * 256 + tid;
    int d = flat >> 4, sg = flat & 15;
    *(f16x8*)&vT[((size_t)bh * DD + d) * NSEQ + c * CHK + sg * 8] =
        *(const f16x8*)&lt[d][sg * 8];
  }
}

// ---------------- k1: phi (fused 2-GEMM + SiLU) ----------------
// M=64 rows/block, 512 thr (8 waves), wave tile 64m x 32f.
__global__ __launch_bounds__(512, 4)
void phi_kernel(const float* __restrict__ q, const float* __restrict__ k,
                const float* __restrict__ b1, const float* __restrict__ b2,
                const _Float16* __restrict__ w1h, const _Float16* __restrict__ w2h,
                _Float16* __restrict__ qp, _Float16* __restrict__ kp) {
  __shared__ __align__(16) _Float16 xs[64][136];  // 17.4 KB
  __shared__ __align__(16) _Float16 hs[64][272];  // 34.8 KB; stride 136 dw == 8 mod 32
  int blk = blockIdx.x;
  const float* src;
  _Float16* dst;
  int rb;
  if (blk < NROWS / 64) { src = q; dst = qp; rb = blk * 64; }
  else                  { src = k; dst = kp; rb = (blk - NROWS / 64) * 64; }
  int tid = threadIdx.x;
  int lane = tid & 63, wv = tid >> 6, lr = lane & 15, lq = lane >> 4;
  int wn = wv;  // f-strip of 32 per wave

  // w1 frags into regs (8 frags = 32 VGPR); latency hides behind x staging
  f16x8 w1r[4][2];
#pragma unroll
  for (int ks = 0; ks < 4; ++ks)
#pragma unroll
    for (int fn = 0; fn < 2; ++fn)
      w1r[ks][fn] = *(const f16x8*)&w1h[(wn * 32 + fn * 16 + lr) * DD + ks * 32 + lq * 8];

  // stage x (64x128 f32 -> f16)
#pragma unroll
  for (int it = 0; it < 4; ++it) {
    int flat = it * 2048 + tid * 4;
    int r = flat >> 7, c = flat & 127;
    float4 xv = *(const float4*)&src[(size_t)(rb + r) * DD + c];
    f16x4 hv = {(_Float16)xv.x, (_Float16)xv.y, (_Float16)xv.z, (_Float16)xv.w};
    *(f16x4*)&xs[r][c] = hv;
  }
  __syncthreads();

  // GEMM1: 64x32 out, K=128, weights in regs
  f32x4 acc[4][2] = {};
#pragma unroll
  for (int ks = 0; ks < 4; ++ks) {
    f16x8 av[4];
#pragma unroll
    for (int im = 0; im < 4; ++im)
      av[im] = *(const f16x8*)&xs[im * 16 + lr][ks * 32 + lq * 8];
#pragma unroll
    for (int fn = 0; fn < 2; ++fn)
#pragma unroll
      for (int im = 0; im < 4; ++im) acc[im][fn] = MFMA16(av[im], w1r[ks][fn], acc[im][fn]);
  }

  // SiLU -> hs (conflict-free scalar writes: quad rows land on disjoint banks)
#pragma unroll
  for (int im = 0; im < 4; ++im)
#pragma unroll
    for (int fn = 0; fn < 2; ++fn) {
      int f = wn * 32 + fn * 16 + lr;
      float bb = b1[f];
      int r0 = im * 16 + lq * 4;
#pragma unroll
      for (int r = 0; r < 4; ++r) {
        float xv = acc[im][fn][r] + bb;
        hs[r0 + r][f] = (_Float16)(xv / (1.0f + __expf(-xv)));
      }
    }

  // prefetch w2 ring for ks=0,1 (overlaps the barrier)
  f16x8 bw[3][2];
#pragma unroll
  for (int fn = 0; fn < 2; ++fn) {
    int g = wn * 32 + fn * 16 + lr;
    bw[0][fn] = *(const f16x8*)&w2h[(size_t)g * FF + 0 * 32 + lq * 8];
    bw[1][fn] = *(const f16x8*)&w2h[(size_t)g * FF + 1 * 32 + lq * 8];
  }
  __syncthreads();

  // GEMM2: 64x32 out, K=256, w2 streamed via 3-deep reg ring
  f32x4 ac2[4][2] = {};
#pragma unroll
  for (int ks = 0; ks < 8; ++ks) {
    if (ks < 6) {
#pragma unroll
      for (int fn = 0; fn < 2; ++fn) {
        int g = wn * 32 + fn * 16 + lr;
        bw[(ks + 2) % 3][fn] = *(const f16x8*)&w2h[(size_t)g * FF + (ks + 2) * 32 + lq * 8];
      }
    }
    f16x8 av[4];
#pragma unroll
    for (int im = 0; im < 4; ++im)
      av[im] = *(const f16x8*)&hs[im * 16 + lr][ks * 32 + lq * 8];
#pragma unroll
    for (int fn = 0; fn < 2; ++fn)
#pragma unroll
      for (int im = 0; im < 4; ++im) ac2[im][fn] = MFMA16(av[im], bw[ks % 3][fn], ac2[im][fn]);
  }

  // epilogue: row-major only (32B segments per quad-row; no transposed scatter)
#pragma unroll
  for (int im = 0; im < 4; ++im)
#pragma unroll
    for (int fn = 0; fn < 2; ++fn) {
      int g = wn * 32 + fn * 16 + lr;
      float bb = b2[g];
      int r0 = im * 16 + lq * 4;
#pragma unroll
      for (int r = 0; r < 4; ++r)
        dst[(size_t)(rb + r0 + r) * FF + g] = (_Float16)(ac2[im][fn][r] + bb);
    }
}

// ---------------- k2: S^T[d][f] per chunk (f-half per block) ----------------
// B-frags assembled from row-major kp tile via scalar LDS reads + pack.
__global__ __launch_bounds__(512, 2)
void s_kernel(const _Float16* __restrict__ vT, const _Float16* __restrict__ kp,
              _Float16* __restrict__ S) {
  __shared__ __align__(16) _Float16 vt[128][136];  // 34.8 KB
  __shared__ __align__(16) _Float16 kr[128][136];  // 34.8 KB  [s][f'] row-major
  int blk = blockIdx.x;
  int fh = blk & 1, c = (blk >> 1) & 31, bh = blk >> 6;
  const _Float16* kpc = kp + ((size_t)bh * NSEQ + c * CHK) * FF;
  int tid = threadIdx.x;
#pragma unroll
  for (int it = 0; it < 4; ++it) {
    int flat = it * 512 + tid;
    int d = flat >> 4, sg = flat & 15;
    *(f16x8*)&vt[d][sg * 8] = *(const f16x8*)&vT[((size_t)bh * DD + d) * NSEQ + c * CHK + sg * 8];
  }
#pragma unroll
  for (int it = 0; it < 4; ++it) {
    int flat = it * 512 + tid;
    int s = flat >> 4, f8 = flat & 15;
    *(f16x8*)&kr[s][f8 * 8] = *(const f16x8*)&kpc[(size_t)s * FF + fh * 128 + f8 * 8];
  }
  __syncthreads();
  int lane = tid & 63, wv = tid >> 6, lr = lane & 15, lq = lane >> 4;
  int wmd = wv & 1, wnf = wv >> 1;  // 2 x 64d, 4 x 32f
  f32x4 acc[4][2] = {};
#pragma unroll
  for (int ks = 0; ks < 4; ++ks) {
    f16x8 av[4];
#pragma unroll
    for (int im = 0; im < 4; ++im)
      av[im] = *(const f16x8*)&vt[wmd * 64 + im * 16 + lr][ks * 32 + lq * 8];
#pragma unroll
    for (int fn = 0; fn < 2; ++fn) {
      int fp = wnf * 32 + fn * 16 + lr;
      f16x8 bv;
#pragma unroll
      for (int j = 0; j < 8; ++j) bv[j] = kr[ks * 32 + lq * 8 + j][fp];
#pragma unroll
      for (int im = 0; im < 4; ++im) acc[im][fn] = MFMA16(av[im], bv, acc[im][fn]);
    }
  }
  _Float16* Sp = S + ((size_t)bh * NC + c) * (size_t)(DD * FF);
#pragma unroll
  for (int im = 0; im < 4; ++im)
#pragma unroll
    for (int fn = 0; fn < 2; ++fn) {
      int f = fh * 128 + wnf * 32 + fn * 16 + lr;
#pragma unroll
      for (int r = 0; r < 4; ++r) {
        int d = wmd * 64 + im * 16 + lq * 4 + r;
        Sp[(size_t)d * FF + f] = (_Float16)acc[im][fn][r];
      }
    }
}

// ---------------- k3: prefix->Wf, suffix in-place (->Wr), vectorized x8 ----
__global__ void prefix_kernel(_Float16* S_Wr, _Float16* __restrict__ Wf) {
  size_t t8 = (size_t)blockIdx.x * 256 + threadIdx.x;
  int bh = (int)(t8 >> 12);
  int df8 = (int)(t8 & 4095);
  size_t base = (size_t)bh * NC * 32768 + (size_t)df8 * 8;
  f16x8 vals[NC];
#pragma unroll
  for (int c = 0; c < NC; ++c) vals[c] = *(const f16x8*)&S_Wr[base + (size_t)c * 32768];
  float run[8] = {};
#pragma unroll
  for (int c = 0; c < NC; ++c) {
    f16x8 w;
#pragma unroll
    for (int j = 0; j < 8; ++j) { w[j] = (_Float16)run[j]; run[j] += (float)vals[c][j]; }
    *(f16x8*)&Wf[base + (size_t)c * 32768] = w;
  }
#pragma unroll
  for (int j = 0; j < 8; ++j) run[j] = 0.f;
#pragma unroll
  for (int c = NC - 1; c >= 0; --c) {
    f16x8 w;
#pragma unroll
    for (int j = 0; j < 8; ++j) { w[j] = (_Float16)run[j]; run[j] += (float)vals[c][j]; }
    *(f16x8*)&S_Wr[base + (size_t)c * 32768] = w;
  }
}

// ---------------- k4: fused phase-2 scan (full chunk per block) ----------------
__global__ __launch_bounds__(512, 2)
void scan_kernel(const _Float16* __restrict__ qp, const _Float16* __restrict__ kp,
                 const _Float16* __restrict__ vT, const _Float16* __restrict__ Wf,
                 const _Float16* __restrict__ Wr, float* __restrict__ out) {
  __shared__ __align__(16) _Float16 vt[128][136];
  __shared__ __align__(16) _Float16 P[128][136];
  int blk = blockIdx.x;
  int c = blk & 31, bh = blk >> 5;
  const _Float16* qpc = qp + ((size_t)bh * NSEQ + c * CHK) * FF;
  const _Float16* kpc = kp + ((size_t)bh * NSEQ + c * CHK) * FF;
  int tid = threadIdx.x, lane = tid & 63, wv = tid >> 6, lr = lane & 15, lq = lane >> 4;
  int wm = wv & 3, wn = wv >> 2;

  f16x8 aq[2][8];
#pragma unroll
  for (int im = 0; im < 2; ++im)
#pragma unroll
    for (int ks = 0; ks < 8; ++ks)
      aq[im][ks] = *(const f16x8*)&qpc[(size_t)(wm * 32 + im * 16 + lr) * FF + ks * 32 + lq * 8];
#pragma unroll
  for (int it = 0; it < 4; ++it) {
    int flat = it * 512 + tid;
    int d = flat >> 4, sg = flat & 15;
    *(f16x8*)&vt[d][sg * 8] = *(const f16x8*)&vT[((size_t)bh * DD + d) * NSEQ + c * CHK + sg * 8];
  }
  f16x8 bk[2][8];
#pragma unroll
  for (int ks = 0; ks < 8; ++ks)
    bk[0][ks] = *(const f16x8*)&kpc[(size_t)(wn * 64 + lr) * FF + ks * 32 + lq * 8];
  f32x4 pacc[2][4] = {};
#pragma unroll
  for (int j = 0; j < 4; ++j) {
    int cur = j & 1;
    if (j < 3)
#pragma unroll
      for (int ks = 0; ks < 8; ++ks)
        bk[cur ^ 1][ks] = *(const f16x8*)&kpc[(size_t)(wn * 64 + (j + 1) * 16 + lr) * FF + ks * 32 + lq * 8];
#pragma unroll
    for (int ks = 0; ks < 8; ++ks)
#pragma unroll
      for (int im = 0; im < 2; ++im)
        pacc[im][j] = MFMA16(aq[im][ks], bk[cur][ks], pacc[im][j]);
  }
#pragma unroll
  for (int im = 0; im < 2; ++im)
#pragma unroll
    for (int j = 0; j < 4; ++j)
#pragma unroll
      for (int r = 0; r < 4; ++r)
        P[wm * 32 + im * 16 + lq * 4 + r][wn * 64 + j * 16 + lr] = (_Float16)pacc[im][j][r];

  const _Float16* Wfc = Wf + ((size_t)bh * NC + c) * (size_t)(DD * FF);
  const _Float16* Wrc = Wr + ((size_t)bh * NC + c) * (size_t)(DD * FF);
  f16x8 bf[8], br[8];
#pragma unroll
  for (int ks = 0; ks < 8; ++ks) {
    int d = wn * 64 + lr;
    bf[ks] = *(const f16x8*)&Wfc[(size_t)d * FF + ks * 32 + lq * 8];
    br[ks] = *(const f16x8*)&Wrc[(size_t)d * FF + ks * 32 + lq * 8];
  }
  __syncthreads();

  f32x4 af[2][4] = {}, ar[2][4] = {};
#pragma unroll
  for (int jd = 0; jd < 4; ++jd) {
#pragma unroll
    for (int ks = 0; ks < 8; ++ks)
#pragma unroll
      for (int im = 0; im < 2; ++im) {
        af[im][jd] = MFMA16(aq[im][ks], bf[ks], af[im][jd]);
        ar[im][jd] = MFMA16(aq[im][ks], br[ks], ar[im][jd]);
      }
    if (jd < 3)
#pragma unroll
      for (int ks = 0; ks < 8; ++ks) {
        int d = wn * 64 + (jd + 1) * 16 + lr;
        bf[ks] = *(const f16x8*)&Wfc[(size_t)d * FF + ks * 32 + lq * 8];
        br[ks] = *(const f16x8*)&Wrc[(size_t)d * FF + ks * 32 + lq * 8];
      }
    {
      int ks = jd;
      f16x8 bv[4];
#pragma unroll
      for (int jd2 = 0; jd2 < 4; ++jd2)
        bv[jd2] = *(const f16x8*)&vt[wn * 64 + jd2 * 16 + lr][ks * 32 + lq * 8];
#pragma unroll
      for (int im = 0; im < 2; ++im) {
        int irow = wm * 32 + im * 16 + lr;
        f16x8 p = *(const f16x8*)&P[irow][ks * 32 + lq * 8];
        f16x8 pf = p, pr = p;
#pragma unroll
        for (int jj = 0; jj < 8; ++jj) {
          int s = ks * 32 + lq * 8 + jj;
          pf[jj] = (s <= irow) ? p[jj] : (_Float16)0.0f;
          pr[jj] = (s >= irow) ? p[jj] : (_Float16)0.0f;
        }
#pragma unroll
        for (int jd2 = 0; jd2 < 4; ++jd2) {
          af[im][jd2] = MFMA16(pf, bv[jd2], af[im][jd2]);
          ar[im][jd2] = MFMA16(pr, bv[jd2], ar[im][jd2]);
        }
      }
    }
  }

  float* oc = out + ((size_t)bh * NSEQ + c * CHK) * DD;
#pragma unroll
  for (int im = 0; im < 2; ++im)
#pragma unroll
    for (int jd = 0; jd < 4; ++jd) {
      int d = wn * 64 + jd * 16 + lr;
#pragma unroll
      for (int r = 0; r < 4; ++r) {
        int il = wm * 32 + im * 16 + lq * 4 + r;
        int gi = c * CHK + il;
        oc[(size_t)il * DD + d] = af[im][jd][r] / (float)(gi + 1) + ar[im][jd][r] / (float)(NSEQ - gi);
      }
    }
}

// ---------------- launcher ----------------
extern "C" void kernel_launch(void* const* d_in, const int* in_sizes, int n_in,
                              void* d_out, int out_size, void* d_ws, size_t ws_size,
                              hipStream_t stream) {
  const float* q  = (const float*)d_in[0];
  const float* k  = (const float*)d_in[1];
  const float* v  = (const float*)d_in[2];
  const float* w1 = (const float*)d_in[3];
  const float* b1 = (const float*)d_in[4];
  const float* w2 = (const float*)d_in[5];
  const float* b2 = (const float*)d_in[6];
  float* out = (float*)d_out;

  char* ws = (char*)d_ws;
  const size_t SZ = 50331648ull;
  _Float16* w1h = (_Float16*)(ws);
  _Float16* w2h = (_Float16*)(ws + 65536);
  _Float16* qp  = (_Float16*)(ws + 196608);
  _Float16* kp  = (_Float16*)(ws + 196608 + SZ);
  _Float16* Wf  = (_Float16*)(ws + 196608 + 2 * SZ);
  _Float16* S   = (_Float16*)(ws + 196608 + 3 * SZ);  // suffix in-place -> Wr
  _Float16* vT  = (_Float16*)(ws + 196608 + 4 * SZ);
  _Float16* Wr  = S;

  prep_kernel<<<dim3(256), dim3(256), 0, stream>>>(w1, w2, w1h, w2h);
  vt_kernel<<<dim3(BH * NC), dim3(256), 0, stream>>>(v, vT);
  phi_kernel<<<dim3(2 * NROWS / 64), dim3(512), 0, stream>>>(q, k, b1, b2, w1h, w2h, qp, kp);
  s_kernel<<<dim3(BH * NC * 2), dim3(512), 0, stream>>>(vT, kp, S);
  prefix_kernel<<<dim3(BH * 4096 / 256), dim3(256), 0, stream>>>(S, Wf);
  scan_kernel<<<dim3(BH * NC), dim3(512), 0, stream>>>(qp, kp, vT, Wf, Wr, out);
}